// Round 15
// baseline (339.315 us; speedup 1.0000x reference)
//
#include <hip/hip_runtime.h>
#include <hip/hip_fp16.h>
#include <math.h>

// EngineOrderFFT via batched Bluestein. |X| = |conv[:, :K]|. M=16384 as a
// 128x128 four-step. R14: ALL passes fused into ONE 1024-block kernel with a
// manual device-scope grid barrier between phases, and batch->XCD pinning
// (batch b on XCD b%8 in every phase) so W1/S2 are produced and consumed in
// the same XCD's L2 within one launch (no kernel-boundary L2 flush).
// Unit bodies = R13-verified kernels (line-complete I/O, fp16 intermediates,
// LDS aliasing, in-block Bhat, 16B/lane vector I/O).
//   W1[b][j][t1][ch] (half2), S2[b][t1][j][ch] (half2, 1/M pre-folded)
//   W1c[b][j][t1] (half2)
// Co-residency: __launch_bounds__(256,4) => <=128 VGPR => 4 blocks/CU
// guaranteed; LDS 22.8KB; grid = 256 CU x 4 = 1024 blocks exactly.

static constexpr int Bn = 64;

#define PI_F 3.14159265358979323846f
#define R2_F 0.70710678118654752f

__device__ __forceinline__ int compute_n(float rpm) {
    return 8192 + (int)floorf((2400.0f / rpm - 1.0f) * 8192.0f);
}
__device__ __forceinline__ float2 cmul(float2 a, float2 b) {
    return make_float2(a.x*b.x - a.y*b.y, a.x*b.y + a.y*b.x);
}
__device__ __forceinline__ float2 cadd(float2 a, float2 b){ return make_float2(a.x+b.x, a.y+b.y); }
__device__ __forceinline__ float2 csub(float2 a, float2 b){ return make_float2(a.x-b.x, a.y-b.y); }
__device__ __forceinline__ float2 shflx1(float2 v) {
    return make_float2(__shfl_xor(v.x, 1, 64), __shfl_xor(v.y, 1, 64));
}
__device__ __forceinline__ int brev7(int x) { return (int)(__brev((unsigned)x) >> 25); }

__device__ __forceinline__ float f2h_bits(float2 a) {
    union { __half2 h; float f; } u;
    u.h = __float22half2_rn(a);
    return u.f;
}
__device__ __forceinline__ float2 h2f_bits(float w) {
    union { float f; __half2 h; } u;
    u.f = w;
    return __half22float2(u.h);
}

#define BF(lo,hi,tw) { float2 _d = csub(lo,hi); lo = cadd(lo,hi); hi = cmul(_d, tw); }
#define BT(lo,hi,tw) { float2 _b = cmul(hi,tw); hi = csub(lo,_b); lo = cadd(lo,_b); }
#define SELC(r,c0,s0,c1,s1) ((r) ? make_float2(c1,s1) : make_float2(c0,s0))
#define IDX(u) ((u) + ((u) >> 4))

__device__ __forceinline__ float2 wtab(const float2* Whi, const float2* Wlo, int m) {
    return cmul(Whi[m >> 7], Wlo[m & 127]);
}

template<bool HZ>
__device__ __forceinline__ void difR(float2 v[8], float2* Lf, int p,
                                     const float2* sWhi) {
    float2 w1 = sWhi[p];
    float2 w2 = cmul(w1, w1);
    float2 w4 = cmul(w2, w2);
    float2 w1b = cmul(w1, make_float2(R2_F,-R2_F));
    float2 w1c = make_float2(w1.y, -w1.x);
    float2 w1d = cmul(w1, make_float2(-R2_F,-R2_F));
    float2 w2i = make_float2(w2.y, -w2.x);
    if (HZ) {
        v[4] = cmul(v[0], w1);
        v[5] = cmul(v[1], w1b);
        v[6] = cmul(v[2], w1c);
        v[7] = cmul(v[3], w1d);
    } else {
        BF(v[0],v[4], w1);
        BF(v[1],v[5], w1b);
        BF(v[2],v[6], w1c);
        BF(v[3],v[7], w1d);
    }
    BF(v[0],v[2], w2);  BF(v[1],v[3], w2i);
    BF(v[4],v[6], w2);  BF(v[5],v[7], w2i);
    BF(v[0],v[1], w4);  BF(v[2],v[3], w4);
    BF(v[4],v[5], w4);  BF(v[6],v[7], w4);
    #pragma unroll
    for (int q = 0; q < 8; ++q) Lf[IDX(p + 16*q)] = v[q];
    int bb = p >> 1, r = p & 1;
    #pragma unroll
    for (int s = 0; s < 8; ++s) v[s] = Lf[IDX(16*bb + r + 2*s)];
    BF(v[0],v[4], SELC(r, 1.f,0.f,                    0.92387953f,-0.38268343f));
    BF(v[1],v[5], SELC(r, 0.70710678f,-0.70710678f,   0.38268343f,-0.92387953f));
    BF(v[2],v[6], SELC(r, 0.f,-1.f,                  -0.38268343f,-0.92387953f));
    BF(v[3],v[7], SELC(r, -0.70710678f,-0.70710678f, -0.92387953f,-0.38268343f));
    BF(v[0],v[2], SELC(r, 1.f,0.f,  0.70710678f,-0.70710678f));
    BF(v[1],v[3], SELC(r, 0.f,-1.f, -0.70710678f,-0.70710678f));
    BF(v[4],v[6], SELC(r, 1.f,0.f,  0.70710678f,-0.70710678f));
    BF(v[5],v[7], SELC(r, 0.f,-1.f, -0.70710678f,-0.70710678f));
    #pragma unroll
    for (int s = 0; s < 8; s += 2) {
        float2 d = csub(v[s], v[s+1]);
        v[s] = cadd(v[s], v[s+1]);
        v[s+1] = r ? make_float2(d.y, -d.x) : d;
    }
    #pragma unroll
    for (int s = 0; s < 8; ++s) {
        float2 o = shflx1(v[s]);
        v[s] = r ? csub(o, v[s]) : cadd(v[s], o);
    }
}

template<bool HOUT>
__device__ __forceinline__ void ditR(float2 v[8], float2* Lf, int p,
                                     const float2* sWhi) {
    int bb = p >> 1, r = p & 1;
    #pragma unroll
    for (int s = 0; s < 8; ++s) {
        float2 o = shflx1(v[s]);
        v[s] = r ? csub(o, v[s]) : cadd(v[s], o);
    }
    #pragma unroll
    for (int s = 0; s < 8; s += 2) {
        float2 bq = v[s+1];
        if (r) bq = make_float2(-bq.y, bq.x);
        v[s+1] = csub(v[s], bq);
        v[s] = cadd(v[s], bq);
    }
    BT(v[0],v[2], SELC(r, 1.f,0.f,  0.70710678f,0.70710678f));
    BT(v[1],v[3], SELC(r, 0.f,1.f, -0.70710678f,0.70710678f));
    BT(v[4],v[6], SELC(r, 1.f,0.f,  0.70710678f,0.70710678f));
    BT(v[5],v[7], SELC(r, 0.f,1.f, -0.70710678f,0.70710678f));
    BT(v[0],v[4], SELC(r, 1.f,0.f,                   0.92387953f,0.38268343f));
    BT(v[1],v[5], SELC(r, 0.70710678f,0.70710678f,   0.38268343f,0.92387953f));
    BT(v[2],v[6], SELC(r, 0.f,1.f,                  -0.38268343f,0.92387953f));
    BT(v[3],v[7], SELC(r, -0.70710678f,0.70710678f, -0.92387953f,0.38268343f));
    #pragma unroll
    for (int s = 0; s < 8; ++s) Lf[IDX(16*bb + r + 2*s)] = v[s];
    #pragma unroll
    for (int q = 0; q < 8; ++q) v[q] = Lf[IDX(p + 16*q)];
    float2 w1 = make_float2(sWhi[p].x, -sWhi[p].y);
    float2 w2 = cmul(w1, w1);
    float2 w4 = cmul(w2, w2);
    float2 w2j = make_float2(-w2.y, w2.x);
    float2 w1b = cmul(w1, make_float2(R2_F, R2_F));
    float2 w1c = make_float2(-w1.y, w1.x);
    float2 w1d = cmul(w1, make_float2(-R2_F, R2_F));
    BT(v[0],v[1], w4); BT(v[2],v[3], w4);
    BT(v[4],v[5], w4); BT(v[6],v[7], w4);
    BT(v[0],v[2], w2);  BT(v[1],v[3], w2j);
    BT(v[4],v[6], w2);  BT(v[5],v[7], w2j);
    if (HOUT) {
        v[0] = cadd(v[0], cmul(v[4], w1));
        v[1] = cadd(v[1], cmul(v[5], w1b));
        v[2] = cadd(v[2], cmul(v[6], w1c));
        v[3] = cadd(v[3], cmul(v[7], w1d));
    } else {
        BT(v[0],v[4], w1);
        BT(v[1],v[5], w1b);
        BT(v[2],v[6], w1c);
        BT(v[3],v[7], w1d);
    }
}

// ---------------- phase units (R13-verified bodies) ----------------

__device__ __forceinline__ void unit_bhat(const float* __restrict__ rpm,
                                          __half2* __restrict__ w1c,
                                          int b, int u, float2* Lw,
                                          const float2* sWhi, const float2* sWlo,
                                          int tid) {
    int g = tid >> 4, p = tid & 15;
    int bb = p >> 1, r = p & 1;
    int t1_0 = u << 4;
    int n = compute_n(rpm[b]);
    int two_n = 2 * n;
    float inv_n = 1.0f / (float)n;
    #pragma unroll
    for (int i = 0; i < 8; ++i) {
        int l = i * 256 + tid;
        int t2 = l >> 4, c = l & 15;
        int t = (t1_0 + c) + (t2 << 7);
        int mm = min(t, 16384 - t);
        int ph = (mm * mm) % two_n;
        float sn, cs; __sincosf(PI_F * (float)ph * inv_n, &sn, &cs);
        Lw[c * 137 + IDX(t2)] = make_float2(cs, sn);
    }
    __syncthreads();
    float2 v[8];
    #pragma unroll
    for (int q = 0; q < 8; ++q) v[q] = Lw[g * 137 + IDX(p + 16*q)];
    difR<false>(v, Lw + g * 137, p, sWhi);
    __syncthreads();
    {
        int t1 = t1_0 + g;
        int k2base = brev7(16*bb + r);
        float2 cur = wtab(sWhi, sWlo, t1 * k2base);
        float2 w8  = wtab(sWhi, sWlo, 8 * t1);
        #pragma unroll
        for (int e = 0; e < 8; ++e) {
            const int s = ((e & 1) << 2) | (e & 2) | ((e & 4) >> 2);
            Lw[(16*bb + r + 2*s) * 17 + g] = cmul(v[s], cur);
            cur = cmul(cur, w8);
        }
    }
    __syncthreads();
    {
        float4* wb4 = (float4*)(w1c + ((size_t)b << 14) + t1_0);
        #pragma unroll
        for (int i = 0; i < 2; ++i) {
            int l = i * 256 + tid;
            int j = l >> 2, w4 = l & 3;
            float4 val;
            val.x = f2h_bits(Lw[j * 17 + w4*4 + 0]);
            val.y = f2h_bits(Lw[j * 17 + w4*4 + 1]);
            val.z = f2h_bits(Lw[j * 17 + w4*4 + 2]);
            val.w = f2h_bits(Lw[j * 17 + w4*4 + 3]);
            wb4[(size_t)j * 32 + w4] = val;
        }
    }
}

__device__ __forceinline__ void unit_k1(const float* __restrict__ x,
                                        const float* __restrict__ rpm,
                                        __half2* __restrict__ w1,
                                        int b, int u, float2* Lw, float2* chirpT,
                                        const float2* sWhi, const float2* sWlo,
                                        int tid) {
    int g = tid >> 4, p = tid & 15;
    int bb = p >> 1, r = p & 1;
    int t1_0 = u << 1;
    int n = compute_n(rpm[b]);
    int two_n = 2 * n;
    float inv_n = 1.0f / (float)n;
    if (tid < 128) {
        int t2 = tid >> 1, t1l = tid & 1;
        int t = t1_0 + t1l + (t2 << 7);
        int ph = (t * t) % two_n;
        float sn, cs; __sincosf(PI_F * (float)ph * inv_n, &sn, &cs);
        chirpT[tid] = make_float2(cs, -sn);
    }
    __syncthreads();
    {
        const float4* xb4 = (const float4*)(x + ((size_t)b << 16));
        int l = tid;                            // l < 256, t2 < 64 only (HZ)
        int t2 = l >> 2, rem = l & 3;
        int t1l = rem >> 1, cp = rem & 1;
        int t = t1_0 + t1l + (t2 << 7);
        float4 xv = xb4[(size_t)t * 2 + cp];
        float2 uu = chirpT[t2 * 2 + t1l];
        int c = t1l * 8 + cp * 4;
        Lw[c * 137 + IDX(t2)]       = make_float2(xv.x * uu.x, xv.x * uu.y);
        Lw[(c + 1) * 137 + IDX(t2)] = make_float2(xv.y * uu.x, xv.y * uu.y);
        Lw[(c + 2) * 137 + IDX(t2)] = make_float2(xv.z * uu.x, xv.z * uu.y);
        Lw[(c + 3) * 137 + IDX(t2)] = make_float2(xv.w * uu.x, xv.w * uu.y);
    }
    __syncthreads();
    float2 v[8];
    #pragma unroll
    for (int q = 0; q < 4; ++q) v[q] = Lw[g * 137 + IDX(p + 16*q)];
    difR<true>(v, Lw + g * 137, p, sWhi);
    __syncthreads();
    {
        int t1 = t1_0 + (g >> 3);
        int k2base = brev7(16*bb + r);
        float2 cur = wtab(sWhi, sWlo, t1 * k2base);
        float2 w8  = wtab(sWhi, sWlo, 8 * t1);
        #pragma unroll
        for (int e = 0; e < 8; ++e) {
            const int s = ((e & 1) << 2) | (e & 2) | ((e & 4) >> 2);
            Lw[(16*bb + r + 2*s) * 17 + g] = cmul(v[s], cur);
            cur = cmul(cur, w8);
        }
    }
    __syncthreads();
    {
        float4* wb4 = (float4*)(w1 + ((size_t)b << 17) + (t1_0 << 3));
        #pragma unroll
        for (int i = 0; i < 2; ++i) {
            int l = i * 256 + tid;
            int j = l >> 2, w4 = l & 3;
            float4 val;
            val.x = f2h_bits(Lw[j * 17 + w4*4 + 0]);
            val.y = f2h_bits(Lw[j * 17 + w4*4 + 1]);
            val.z = f2h_bits(Lw[j * 17 + w4*4 + 2]);
            val.w = f2h_bits(Lw[j * 17 + w4*4 + 3]);
            wb4[(size_t)j * 256 + w4] = val;
        }
    }
}

__device__ __forceinline__ void unit_k2(const __half2* __restrict__ w1,
                                        const __half2* __restrict__ w1c,
                                        __half2* __restrict__ s2,
                                        int b, int u, float2* Lw, float2* Wsc,
                                        const float2* sWhi, const float2* sWlo,
                                        int tid) {
    int g = tid >> 4, p = tid & 15;
    int j0 = u << 1;
    float2 vb[8];
    if (g < 2) {
        const __half2* wc = w1c + ((size_t)b << 14) + ((size_t)(j0 + g) << 7);
        #pragma unroll
        for (int q = 0; q < 8; ++q) vb[q] = __half22float2(wc[p + 16*q]);
    }
    {
        const float4* rb4 = (const float4*)(w1 + ((size_t)b << 17) + ((size_t)j0 << 10));
        #pragma unroll
        for (int i = 0; i < 2; ++i) {
            int l = i * 256 + tid;
            int jl = l >> 8, rem = l & 255, t1 = rem >> 1, ch4 = rem & 1;
            float4 d = rb4[l];
            int c = jl * 8 + ch4 * 4;
            Lw[(c + 0) * 137 + IDX(t1)] = h2f_bits(d.x);
            Lw[(c + 1) * 137 + IDX(t1)] = h2f_bits(d.y);
            Lw[(c + 2) * 137 + IDX(t1)] = h2f_bits(d.z);
            Lw[(c + 3) * 137 + IDX(t1)] = h2f_bits(d.w);
        }
    }
    __syncthreads();
    if (g < 2) {
        difR<false>(vb, Wsc + g * 137, p, sWhi);
        #pragma unroll
        for (int s = 0; s < 8; ++s) Wsc[g * 137 + s * 17 + p] = vb[s];
    }
    float2* Lf = Lw + g * 137;
    float2 v[8];
    #pragma unroll
    for (int q = 0; q < 8; ++q) v[q] = Lf[IDX(p + 16*q)];
    difR<false>(v, Lf, p, sWhi);
    __syncthreads();
    {
        int jl = g >> 3;
        #pragma unroll
        for (int s = 0; s < 8; ++s) v[s] = cmul(v[s], Wsc[jl * 137 + s * 17 + p]);
    }
    ditR<false>(v, Lf, p, sWhi);
    int j = j0 + (g >> 3);
    int k2v = brev7(j);
    __syncthreads();
    {
        float2 cur = wtab(sWhi, sWlo, k2v * p);
        float2 w16 = wtab(sWhi, sWlo, 16 * k2v);
        #pragma unroll
        for (int q = 0; q < 8; ++q) {
            float2 tw = make_float2(cur.x * (1.0f/16384.0f), -cur.y * (1.0f/16384.0f));
            Lw[(p + 16*q) * 17 + g] = cmul(v[q], tw);
            cur = cmul(cur, w16);
        }
    }
    __syncthreads();
    {
        float4* sb4 = (float4*)(s2 + ((size_t)b << 17));
        #pragma unroll
        for (int i = 0; i < 2; ++i) {
            int l = i * 256 + tid;
            int t1 = l >> 2, w4 = l & 3;
            float4 val;
            val.x = f2h_bits(Lw[t1 * 17 + w4*4 + 0]);
            val.y = f2h_bits(Lw[t1 * 17 + w4*4 + 1]);
            val.z = f2h_bits(Lw[t1 * 17 + w4*4 + 2]);
            val.w = f2h_bits(Lw[t1 * 17 + w4*4 + 3]);
            sb4[(size_t)t1 * 256 + (j0 << 1) + w4] = val;
        }
    }
}

__device__ __forceinline__ void unit_k3(const __half2* __restrict__ s2,
                                        float* __restrict__ outF,
                                        int b, int u, float2* Lw,
                                        const float2* sWhi, const float2* sWlo,
                                        int tid) {
    int g = tid >> 4, p = tid & 15;
    int bb = p >> 1, r = p & 1;
    int t1_0 = u << 1;
    {
        const float4* rb4 = (const float4*)(s2 + ((size_t)b << 17) + ((size_t)t1_0 << 10));
        #pragma unroll
        for (int i = 0; i < 2; ++i) {
            int l = i * 256 + tid;
            int t1l = l >> 8, rem = l & 255, j = rem >> 1, ch4 = rem & 1;
            float4 d = rb4[l];
            int c = t1l * 8 + ch4 * 4;
            Lw[(c + 0) * 137 + IDX(j)] = h2f_bits(d.x);
            Lw[(c + 1) * 137 + IDX(j)] = h2f_bits(d.y);
            Lw[(c + 2) * 137 + IDX(j)] = h2f_bits(d.z);
            Lw[(c + 3) * 137 + IDX(j)] = h2f_bits(d.w);
        }
    }
    __syncthreads();
    float2 v[8];
    {
        float2* Lf = Lw + g * 137;
        #pragma unroll
        for (int s = 0; s < 8; ++s) v[s] = Lf[IDX(16*bb + r + 2*s)];
        ditR<true>(v, Lf, p, sWhi);
    }
    __syncthreads();
    float* Lsf = (float*)Lw;
    #pragma unroll
    for (int q = 0; q < 4; ++q) {
        float2 z = v[q];
        Lsf[(p + 16*q) * 20 + g] = sqrtf(z.x*z.x + z.y*z.y);
    }
    __syncthreads();
    {
        float4* ob4 = (float4*)(outF + ((size_t)b << 16) + (t1_0 << 3));
        int t2 = tid >> 2, t1l = (tid >> 1) & 1, ch4 = tid & 1;
        int base = t2 * 20 + t1l * 8 + ch4 * 4;
        float4 val = make_float4(Lsf[base], Lsf[base + 1], Lsf[base + 2], Lsf[base + 3]);
        ob4[t2 * 256 + t1l * 2 + ch4] = val;
    }
}

// ---------------- grid barrier ----------------
__device__ __forceinline__ void gridbar(unsigned* bar, unsigned target) {
    __syncthreads();
    if (threadIdx.x == 0) {
        __threadfence();                        // release phase writes
        atomicAdd(bar, 1u);
        while (__hip_atomic_load(bar, __ATOMIC_ACQUIRE, __HIP_MEMORY_SCOPE_AGENT) < target) {
            __builtin_amdgcn_s_sleep(8);
        }
    }
    __syncthreads();
}

// ---------------- fused kernel ----------------
__global__ __launch_bounds__(256, 4) void eofft_all(const float* __restrict__ x,
                                                    const float* __restrict__ rpm,
                                                    __half2* __restrict__ w1,
                                                    __half2* __restrict__ w1c,
                                                    __half2* __restrict__ s2,
                                                    float* __restrict__ outF,
                                                    unsigned* __restrict__ bar) {
    __shared__ float2 Lw[16 * 137];
    __shared__ float2 Wsc[2 * 137];
    __shared__ float2 chirpT[128];
    __shared__ float2 sWhi[128];
    __shared__ float2 sWlo[128];
    int tid = threadIdx.x;
    if (tid < 128) {
        float sn, cs; __sincosf(PI_F * (float)tid * (1.0f/64.0f), &sn, &cs);
        sWhi[tid] = make_float2(cs, -sn);
    } else {
        int m = tid - 128;
        float sn, cs; __sincosf(PI_F * (float)m * (1.0f/8192.0f), &sn, &cs);
        sWlo[m] = make_float2(cs, -sn);
    }
    int xcd = blockIdx.x & 7;                  // batch b runs on XCD b%8, all phases
    int slot = blockIdx.x >> 3;                // 0..127
    __syncthreads();

    // phase 1: per batch 72 units (0..7 bhat t1-groups, 8..71 k1 t1-pairs)
    for (int e = slot; e < 8 * 72; e += 128) {
        int m = e / 72, u = e - m * 72;
        int b = xcd + (m << 3);
        if (u < 8) unit_bhat(rpm, w1c, b, u, Lw, sWhi, sWlo, tid);
        else       unit_k1(x, rpm, w1, b, u - 8, Lw, chirpT, sWhi, sWlo, tid);
        __syncthreads();
    }
    gridbar(bar, 1024u);

    // phase 2: per batch 64 j-slice units
    for (int e = slot; e < 8 * 64; e += 128) {
        int b = xcd + ((e >> 6) << 3), u = e & 63;
        unit_k2(w1, w1c, s2, b, u, Lw, Wsc, sWhi, sWlo, tid);
        __syncthreads();
    }
    gridbar(bar, 2048u);

    // phase 3: per batch 64 t1-pair units
    for (int e = slot; e < 8 * 64; e += 128) {
        int b = xcd + ((e >> 6) << 3), u = e & 63;
        unit_k3(s2, outF, b, u, Lw, sWhi, sWlo, tid);
        __syncthreads();
    }
}

// ---------------- launch ----------------
extern "C" void kernel_launch(void* const* d_in, const int* in_sizes, int n_in,
                              void* d_out, int out_size, void* d_ws, size_t ws_size,
                              hipStream_t stream) {
    const float* x   = (const float*)d_in[0];
    const float* rpm = (const float*)d_in[1];
    float* outF = (float*)d_out;
    __half2* w1  = (__half2*)d_ws;                               // 32 MiB
    __half2* s2  = w1 + (size_t)Bn * 131072;                     // 32 MiB
    __half2* w1c = s2 + (size_t)Bn * 131072;                     // 4 MiB
    unsigned* bar = (unsigned*)(w1c + (size_t)Bn * 16384);

    hipMemsetAsync(bar, 0, 64, stream);
    eofft_all<<<1024, 256, 0, stream>>>(x, rpm, w1, w1c, s2, outF, bar);
}

// Round 16
// 71.770 us; speedup vs baseline: 4.7278x; 4.7278x over previous
//
#include <hip/hip_runtime.h>
#include <hip/hip_fp16.h>
#include <math.h>

// EngineOrderFFT via batched Bluestein. |X| = |conv[:, :K]|. M=16384 as a
// 128x128 four-step, 3 kernel launches, line-complete global I/O (R8),
// fp16 intermediates (R9), LDS aliasing + in-block Bhat (R10), 16B/lane
// vector I/O (R12). R14's fused-barrier mono regressed 5x (device-scope
// fences force per-XCD L2 writebacks) -- reverted.
// R15 = R13 + (a) k1 drops chirpT table (per-lane sincos, LDS 19.1KB ->
// 8 blocks/CU); (b) k3 2-unit T14 pipelining (prefetch next unit's S2
// loads into registers before current unit's FFT; grid = exactly one
// co-resident round).
//   W1[b][j][t1][ch] (half2), S2[b][t1][j][ch] (half2, 1/M pre-folded)
//   W1c[b][j][t1] (half2)

static constexpr int Bn = 64;

#define PI_F 3.14159265358979323846f
#define R2_F 0.70710678118654752f

__device__ __forceinline__ int compute_n(float rpm) {
    // ref: pad = floor((40*60/rpm - 1)*8192) in f32; n = 8192 + pad
    return 8192 + (int)floorf((2400.0f / rpm - 1.0f) * 8192.0f);
}
__device__ __forceinline__ float2 cmul(float2 a, float2 b) {
    return make_float2(a.x*b.x - a.y*b.y, a.x*b.y + a.y*b.x);
}
__device__ __forceinline__ float2 cadd(float2 a, float2 b){ return make_float2(a.x+b.x, a.y+b.y); }
__device__ __forceinline__ float2 csub(float2 a, float2 b){ return make_float2(a.x-b.x, a.y-b.y); }
__device__ __forceinline__ float2 shflx1(float2 v) {
    return make_float2(__shfl_xor(v.x, 1, 64), __shfl_xor(v.y, 1, 64));
}
__device__ __forceinline__ int brev7(int x) { return (int)(__brev((unsigned)x) >> 25); }

// fp16 pack/unpack via 32-bit bit-cast (keeps global I/O in float4 lanes)
__device__ __forceinline__ float f2h_bits(float2 a) {
    union { __half2 h; float f; } u;
    u.h = __float22half2_rn(a);
    return u.f;
}
__device__ __forceinline__ float2 h2f_bits(float w) {
    union { float f; __half2 h; } u;
    u.f = w;
    return __half22float2(u.h);
}

#define BF(lo,hi,tw) { float2 _d = csub(lo,hi); lo = cadd(lo,hi); hi = cmul(_d, tw); }
#define BT(lo,hi,tw) { float2 _b = cmul(hi,tw); hi = csub(lo,_b); lo = cadd(lo,_b); }
#define SELC(r,c0,s0,c1,s1) ((r) ? make_float2(c1,s1) : make_float2(c0,s0))
#define IDX(u) ((u) + ((u) >> 4))          // row-local pad (R2/R3-proven)

// W_M^{-m}: Whi[m]=exp(-i*pi*m/64), Wlo[m]=exp(-i*pi*m/8192)
__device__ __forceinline__ float2 wtab(const float2* Whi, const float2* Wlo, int m) {
    return cmul(Whi[m >> 7], Wlo[m & 127]);
}

// ====== row-local cores. Lf = per-FFT scratch region (>=136 f2) ======
// HZ: inputs v[4..7] are implicit zeros (not loaded).
template<bool HZ>
__device__ __forceinline__ void difR(float2 v[8], float2* Lf, int p,
                                     const float2* sWhi) {
    float2 w1 = sWhi[p];                        // exp(-i*pi*p/64)
    float2 w2 = cmul(w1, w1);
    float2 w4 = cmul(w2, w2);
    float2 w1b = cmul(w1, make_float2(R2_F,-R2_F));
    float2 w1c = make_float2(w1.y, -w1.x);
    float2 w1d = cmul(w1, make_float2(-R2_F,-R2_F));
    float2 w2i = make_float2(w2.y, -w2.x);
    if (HZ) {
        v[4] = cmul(v[0], w1);
        v[5] = cmul(v[1], w1b);
        v[6] = cmul(v[2], w1c);
        v[7] = cmul(v[3], w1d);
    } else {
        BF(v[0],v[4], w1);
        BF(v[1],v[5], w1b);
        BF(v[2],v[6], w1c);
        BF(v[3],v[7], w1d);
    }
    BF(v[0],v[2], w2);  BF(v[1],v[3], w2i);
    BF(v[4],v[6], w2);  BF(v[5],v[7], w2i);
    BF(v[0],v[1], w4);  BF(v[2],v[3], w4);
    BF(v[4],v[5], w4);  BF(v[6],v[7], w4);
    #pragma unroll
    for (int q = 0; q < 8; ++q) Lf[IDX(p + 16*q)] = v[q];
    int bb = p >> 1, r = p & 1;
    #pragma unroll
    for (int s = 0; s < 8; ++s) v[s] = Lf[IDX(16*bb + r + 2*s)];
    BF(v[0],v[4], SELC(r, 1.f,0.f,                    0.92387953f,-0.38268343f));
    BF(v[1],v[5], SELC(r, 0.70710678f,-0.70710678f,   0.38268343f,-0.92387953f));
    BF(v[2],v[6], SELC(r, 0.f,-1.f,                  -0.38268343f,-0.92387953f));
    BF(v[3],v[7], SELC(r, -0.70710678f,-0.70710678f, -0.92387953f,-0.38268343f));
    BF(v[0],v[2], SELC(r, 1.f,0.f,  0.70710678f,-0.70710678f));
    BF(v[1],v[3], SELC(r, 0.f,-1.f, -0.70710678f,-0.70710678f));
    BF(v[4],v[6], SELC(r, 1.f,0.f,  0.70710678f,-0.70710678f));
    BF(v[5],v[7], SELC(r, 0.f,-1.f, -0.70710678f,-0.70710678f));
    #pragma unroll
    for (int s = 0; s < 8; s += 2) {
        float2 d = csub(v[s], v[s+1]);
        v[s] = cadd(v[s], v[s+1]);
        v[s+1] = r ? make_float2(d.y, -d.x) : d;
    }
    #pragma unroll
    for (int s = 0; s < 8; ++s) {
        float2 o = shflx1(v[s]);
        v[s] = r ? csub(o, v[s]) : cadd(v[s], o);
    }
}

// HOUT: only lo outputs v[0..3] of the final stage are produced.
template<bool HOUT>
__device__ __forceinline__ void ditR(float2 v[8], float2* Lf, int p,
                                     const float2* sWhi) {
    int bb = p >> 1, r = p & 1;
    #pragma unroll
    for (int s = 0; s < 8; ++s) {
        float2 o = shflx1(v[s]);
        v[s] = r ? csub(o, v[s]) : cadd(v[s], o);
    }
    #pragma unroll
    for (int s = 0; s < 8; s += 2) {
        float2 bq = v[s+1];
        if (r) bq = make_float2(-bq.y, bq.x);
        v[s+1] = csub(v[s], bq);
        v[s] = cadd(v[s], bq);
    }
    BT(v[0],v[2], SELC(r, 1.f,0.f,  0.70710678f,0.70710678f));
    BT(v[1],v[3], SELC(r, 0.f,1.f, -0.70710678f,0.70710678f));
    BT(v[4],v[6], SELC(r, 1.f,0.f,  0.70710678f,0.70710678f));
    BT(v[5],v[7], SELC(r, 0.f,1.f, -0.70710678f,0.70710678f));
    BT(v[0],v[4], SELC(r, 1.f,0.f,                   0.92387953f,0.38268343f));
    BT(v[1],v[5], SELC(r, 0.70710678f,0.70710678f,   0.38268343f,0.92387953f));
    BT(v[2],v[6], SELC(r, 0.f,1.f,                  -0.38268343f,0.92387953f));
    BT(v[3],v[7], SELC(r, -0.70710678f,0.70710678f, -0.92387953f,0.38268343f));
    #pragma unroll
    for (int s = 0; s < 8; ++s) Lf[IDX(16*bb + r + 2*s)] = v[s];
    #pragma unroll
    for (int q = 0; q < 8; ++q) v[q] = Lf[IDX(p + 16*q)];
    float2 w1 = make_float2(sWhi[p].x, -sWhi[p].y);   // exp(+i*pi*p/64)
    float2 w2 = cmul(w1, w1);
    float2 w4 = cmul(w2, w2);
    float2 w2j = make_float2(-w2.y, w2.x);
    float2 w1b = cmul(w1, make_float2(R2_F, R2_F));
    float2 w1c = make_float2(-w1.y, w1.x);
    float2 w1d = cmul(w1, make_float2(-R2_F, R2_F));
    BT(v[0],v[1], w4); BT(v[2],v[3], w4);
    BT(v[4],v[5], w4); BT(v[6],v[7], w4);
    BT(v[0],v[2], w2);  BT(v[1],v[3], w2j);
    BT(v[4],v[6], w2);  BT(v[5],v[7], w2j);
    if (HOUT) {
        v[0] = cadd(v[0], cmul(v[4], w1));
        v[1] = cadd(v[1], cmul(v[5], w1b));
        v[2] = cadd(v[2], cmul(v[6], w1c));
        v[3] = cadd(v[3], cmul(v[7], w1d));
    } else {
        BT(v[0],v[4], w1);
        BT(v[1],v[5], w1b);
        BT(v[2],v[6], w1c);
        BT(v[3],v[7], w1d);
    }
}

__device__ __forceinline__ void load_tabs(float2* sWhi, float2* sWlo, int tid) {
    if (tid < 128) {
        float sn, cs; __sincosf(PI_F * (float)tid * (1.0f/64.0f), &sn, &cs);
        sWhi[tid] = make_float2(cs, -sn);
    } else if (tid < 256) {
        int m = tid - 128;
        float sn, cs; __sincosf(PI_F * (float)m * (1.0f/8192.0f), &sn, &cs);
        sWlo[m] = make_float2(cs, -sn);
    }
}

// ---- K1B: merged launch. Blocks [0, Bn*8): bhat pass 1 (chirp -> FFT over
// t2 -> twiddle -> W1c fp16). Blocks [Bn*8, ...): main K1 (x -> chirp ->
// FFT over t2 -> twiddle -> W1 fp16). 256 thr, 19.1 KB LDS (8 blocks/CU).
__global__ __launch_bounds__(256) void k1b(const float* __restrict__ x,
                                           const float* __restrict__ rpm,
                                           __half2* __restrict__ w1,
                                           __half2* __restrict__ w1c) {
    __shared__ float2 Lw[16 * 137];            // aliased as Ls[128*17] later
    __shared__ float2 sWhi[128];
    __shared__ float2 sWlo[128];
    int tid = threadIdx.x;
    int g = tid >> 4, p = tid & 15;
    int bb = p >> 1, r = p & 1;

    load_tabs(sWhi, sWlo, tid);

    if (blockIdx.x < Bn * 8) {
        // ======== bhat pass 1 ========
        int b = blockIdx.x >> 3;
        int t1_0 = (blockIdx.x & 7) << 4;
        int n = compute_n(rpm[b]);
        int two_n = 2 * n;
        float inv_n = 1.0f / (float)n;
        #pragma unroll
        for (int i = 0; i < 8; ++i) {
            int l = i * 256 + tid;
            int t2 = l >> 4, c = l & 15;
            int t = (t1_0 + c) + (t2 << 7);
            int mm = min(t, 16384 - t);
            int ph = (mm * mm) % two_n;
            float sn, cs; __sincosf(PI_F * (float)ph * inv_n, &sn, &cs);
            Lw[c * 137 + IDX(t2)] = make_float2(cs, sn);   // exp(+i b_phase)
        }
        __syncthreads();
        float2 v[8];
        #pragma unroll
        for (int q = 0; q < 8; ++q) v[q] = Lw[g * 137 + IDX(p + 16*q)];
        difR<false>(v, Lw + g * 137, p, sWhi);
        __syncthreads();                        // Lw dead -> alias as Ls
        {
            int t1 = t1_0 + g;
            int k2base = brev7(16*bb + r);
            float2 cur = wtab(sWhi, sWlo, t1 * k2base);
            float2 w8  = wtab(sWhi, sWlo, 8 * t1);
            #pragma unroll
            for (int e = 0; e < 8; ++e) {
                const int s = ((e & 1) << 2) | (e & 2) | ((e & 4) >> 2); // brev3
                Lw[(16*bb + r + 2*s) * 17 + g] = cmul(v[s], cur);
                cur = cmul(cur, w8);
            }
        }
        __syncthreads();
        {
            // w1c fp16: per j, 16 half2 = 4 float4 for this t1-group
            float4* wb4 = (float4*)(w1c + ((size_t)b << 14) + t1_0);
            #pragma unroll
            for (int i = 0; i < 2; ++i) {
                int l = i * 256 + tid;          // l < 512
                int j = l >> 2, w4 = l & 3;
                float4 val;
                val.x = f2h_bits(Lw[j * 17 + w4*4 + 0]);
                val.y = f2h_bits(Lw[j * 17 + w4*4 + 1]);
                val.z = f2h_bits(Lw[j * 17 + w4*4 + 2]);
                val.w = f2h_bits(Lw[j * 17 + w4*4 + 3]);
                wb4[(size_t)j * 32 + w4] = val;
            }
        }
        return;
    }

    // ======== main K1 ========
    int bid = blockIdx.x - Bn * 8;
    int b = bid >> 6;
    int t1_0 = (bid & 63) << 1;
    int n = compute_n(rpm[b]);
    int two_n = 2 * n;
    float inv_n = 1.0f / (float)n;
    {
        // x loads: float4 = 4 ch, 16 B/lane; ONLY t2 < 64 (HZ trim).
        // per-lane chirp (chirpT table removed; one sincosf per lane).
        const float4* xb4 = (const float4*)(x + ((size_t)b << 16));
        int l = tid;                            // l < 256
        int t2 = l >> 2, rem = l & 3;
        int t1l = rem >> 1, cp = rem & 1;
        int t = t1_0 + t1l + (t2 << 7);         // t < 8192
        int ph = (t * t) % two_n;
        float sn, cs; __sincosf(PI_F * (float)ph * inv_n, &sn, &cs);
        float2 uu = make_float2(cs, -sn);       // exp(-i a_phase)
        float4 xv = xb4[(size_t)t * 2 + cp];
        int c = t1l * 8 + cp * 4;
        Lw[c * 137 + IDX(t2)]       = make_float2(xv.x * uu.x, xv.x * uu.y);
        Lw[(c + 1) * 137 + IDX(t2)] = make_float2(xv.y * uu.x, xv.y * uu.y);
        Lw[(c + 2) * 137 + IDX(t2)] = make_float2(xv.z * uu.x, xv.z * uu.y);
        Lw[(c + 3) * 137 + IDX(t2)] = make_float2(xv.w * uu.x, xv.w * uu.y);
    }
    __syncthreads();
    float2 v[8];
    #pragma unroll
    for (int q = 0; q < 4; ++q) v[q] = Lw[g * 137 + IDX(p + 16*q)];
    difR<true>(v, Lw + g * 137, p, sWhi);
    __syncthreads();                            // Lw dead -> alias as Ls
    {
        int t1 = t1_0 + (g >> 3);
        int k2base = brev7(16*bb + r);
        float2 cur = wtab(sWhi, sWlo, t1 * k2base);
        float2 w8  = wtab(sWhi, sWlo, 8 * t1);
        #pragma unroll
        for (int e = 0; e < 8; ++e) {
            const int s = ((e & 1) << 2) | (e & 2) | ((e & 4) >> 2); // brev3(e)
            Lw[(16*bb + r + 2*s) * 17 + g] = cmul(v[s], cur);
            cur = cmul(cur, w8);
        }
    }
    __syncthreads();
    {
        // W1 writes: float4 = 4 half2, 16 B/lane; per j 64 B contiguous
        float4* wb4 = (float4*)(w1 + ((size_t)b << 17) + (t1_0 << 3));
        #pragma unroll
        for (int i = 0; i < 2; ++i) {
            int l = i * 256 + tid;              // l < 512
            int j = l >> 2, w4 = l & 3;
            float4 val;
            val.x = f2h_bits(Lw[j * 17 + w4*4 + 0]);
            val.y = f2h_bits(Lw[j * 17 + w4*4 + 1]);
            val.z = f2h_bits(Lw[j * 17 + w4*4 + 2]);
            val.w = f2h_bits(Lw[j * 17 + w4*4 + 3]);
            wb4[(size_t)j * 256 + w4] = val;
        }
    }
}

// ---- K2: block=(b, 2-j-slice), 256 thr (exact R13).
// W1 -> FFT over t1 -> *Bhat(in-block from W1c by groups g<2) -> iFFT ->
// twiddle*(1/M) -> S2 ----
__global__ __launch_bounds__(256) void k2(const __half2* __restrict__ w1,
                                          const __half2* __restrict__ w1c,
                                          __half2* __restrict__ s2) {
    __shared__ float2 Lw[16 * 137];            // aliased as Ls[128*17] later
    __shared__ float2 Wsc[2 * 137];            // Bhat scratch+result [s*17+p]
    __shared__ float2 sWhi[128];
    __shared__ float2 sWlo[128];
    int tid = threadIdx.x;
    int g = tid >> 4, p = tid & 15;             // g in [0,16)
    int b = blockIdx.x >> 6;
    int j0 = (blockIdx.x & 63) << 1;

    load_tabs(sWhi, sWlo, tid);
    float2 vb[8];
    if (g < 2) {
        const __half2* wc = w1c + ((size_t)b << 14) + ((size_t)(j0 + g) << 7);
        #pragma unroll
        for (int q = 0; q < 8; ++q) vb[q] = __half22float2(wc[p + 16*q]);
    }
    {
        const float4* rb4 = (const float4*)(w1 + ((size_t)b << 17) + ((size_t)j0 << 10));
        #pragma unroll
        for (int i = 0; i < 2; ++i) {
            int l = i * 256 + tid;              // l < 512
            int jl = l >> 8, rem = l & 255, t1 = rem >> 1, ch4 = rem & 1;
            float4 d = rb4[l];
            int c = jl * 8 + ch4 * 4;
            Lw[(c + 0) * 137 + IDX(t1)] = h2f_bits(d.x);
            Lw[(c + 1) * 137 + IDX(t1)] = h2f_bits(d.y);
            Lw[(c + 2) * 137 + IDX(t1)] = h2f_bits(d.z);
            Lw[(c + 3) * 137 + IDX(t1)] = h2f_bits(d.w);
        }
    }
    __syncthreads();
    if (g < 2) {
        difR<false>(vb, Wsc + g * 137, p, sWhi);
        #pragma unroll
        for (int s = 0; s < 8; ++s) Wsc[g * 137 + s * 17 + p] = vb[s];
    }
    float2* Lf = Lw + g * 137;
    float2 v[8];
    #pragma unroll
    for (int q = 0; q < 8; ++q) v[q] = Lf[IDX(p + 16*q)];
    difR<false>(v, Lf, p, sWhi);
    __syncthreads();                            // Wsc published
    {
        int jl = g >> 3;
        #pragma unroll
        for (int s = 0; s < 8; ++s) v[s] = cmul(v[s], Wsc[jl * 137 + s * 17 + p]);
    }
    ditR<false>(v, Lf, p, sWhi);
    int j = j0 + (g >> 3);
    int k2v = brev7(j);
    __syncthreads();                            // Lf scratch done -> alias Ls
    {
        float2 cur = wtab(sWhi, sWlo, k2v * p);
        float2 w16 = wtab(sWhi, sWlo, 16 * k2v);
        #pragma unroll
        for (int q = 0; q < 8; ++q) {
            float2 tw = make_float2(cur.x * (1.0f/16384.0f), -cur.y * (1.0f/16384.0f));
            Lw[(p + 16*q) * 17 + g] = cmul(v[q], tw);
            cur = cmul(cur, w16);
        }
    }
    __syncthreads();
    {
        float4* sb4 = (float4*)(s2 + ((size_t)b << 17));
        #pragma unroll
        for (int i = 0; i < 2; ++i) {
            int l = i * 256 + tid;              // l < 512
            int t1 = l >> 2, w4 = l & 3;
            float4 val;
            val.x = f2h_bits(Lw[t1 * 17 + w4*4 + 0]);
            val.y = f2h_bits(Lw[t1 * 17 + w4*4 + 1]);
            val.z = f2h_bits(Lw[t1 * 17 + w4*4 + 2]);
            val.w = f2h_bits(Lw[t1 * 17 + w4*4 + 3]);
            sb4[(size_t)t1 * 256 + (j0 << 1) + w4] = val;
        }
    }
}

// ---- K3: block=(b, t1-quad), 2 pipelined units (T14 async-stage). ----
// Each unit = R13's k3 body (t1-pair): S2 -> iFFT over j -> |.| -> out.
__global__ __launch_bounds__(256) void k3(const __half2* __restrict__ s2,
                                          float* __restrict__ outF) {
    __shared__ float2 Lw[16 * 137];            // aliased as float Lsf later
    __shared__ float2 sWhi[128];
    __shared__ float2 sWlo[128];
    int tid = threadIdx.x;
    int g = tid >> 4, p = tid & 15;
    int bb = p >> 1, r = p & 1;
    int b = blockIdx.x >> 5;
    int quad = (blockIdx.x & 31) << 2;          // units at quad, quad+2

    load_tabs(sWhi, sWlo, tid);
    // prefetch unit 0 (2 float4 per thread)
    float4 d0[2], d1[2];
    {
        const float4* rb4 = (const float4*)(s2 + ((size_t)b << 17) + ((size_t)quad << 10));
        d0[0] = rb4[tid];
        d0[1] = rb4[256 + tid];
    }
    #pragma unroll
    for (int uu = 0; uu < 2; ++uu) {
        int t1_0 = quad + uu * 2;
        if (uu == 0) {
            // issue unit 1's loads now; latency hides under unit 0's FFT
            const float4* rb4n = (const float4*)(s2 + ((size_t)b << 17) + ((size_t)(quad + 2) << 10));
            d1[0] = rb4n[tid];
            d1[1] = rb4n[256 + tid];
        }
        __syncthreads();                        // prev unit's LDS fully read
        // write staged registers to LDS (fp16 -> f32)
        #pragma unroll
        for (int i = 0; i < 2; ++i) {
            int l = i * 256 + tid;              // l < 512
            int t1l = l >> 8, rem = l & 255, j = rem >> 1, ch4 = rem & 1;
            float4 d = d0[i];
            int c = t1l * 8 + ch4 * 4;
            Lw[(c + 0) * 137 + IDX(j)] = h2f_bits(d.x);
            Lw[(c + 1) * 137 + IDX(j)] = h2f_bits(d.y);
            Lw[(c + 2) * 137 + IDX(j)] = h2f_bits(d.z);
            Lw[(c + 3) * 137 + IDX(j)] = h2f_bits(d.w);
        }
        __syncthreads();
        float2 v[8];
        {
            float2* Lf = Lw + g * 137;
            #pragma unroll
            for (int s = 0; s < 8; ++s) v[s] = Lf[IDX(16*bb + r + 2*s)];
            ditR<true>(v, Lf, p, sWhi);
        }
        __syncthreads();                        // Lw dead -> alias float Lsf
        float* Lsf = (float*)Lw;
        #pragma unroll
        for (int q = 0; q < 4; ++q) {
            // v[q] = z[m = t1 + 128*(p+16q)], q<4 (1/M applied in k2)
            float2 z = v[q];
            Lsf[(p + 16*q) * 20 + g] = sqrtf(z.x*z.x + z.y*z.y);
        }
        __syncthreads();
        {
            // out writes: float4 = 4 ch, 16 B/lane; 64 B line-complete per m
            float4* ob4 = (float4*)(outF + ((size_t)b << 16) + (t1_0 << 3));
            int t2 = tid >> 2, t1l = (tid >> 1) & 1, ch4 = tid & 1;
            int base = t2 * 20 + t1l * 8 + ch4 * 4;
            float4 val = make_float4(Lsf[base], Lsf[base + 1], Lsf[base + 2], Lsf[base + 3]);
            ob4[t2 * 256 + t1l * 2 + ch4] = val;
        }
        d0[0] = d1[0];
        d0[1] = d1[1];
    }
}

// ---------------- launch ----------------
extern "C" void kernel_launch(void* const* d_in, const int* in_sizes, int n_in,
                              void* d_out, int out_size, void* d_ws, size_t ws_size,
                              hipStream_t stream) {
    const float* x   = (const float*)d_in[0];
    const float* rpm = (const float*)d_in[1];
    float* outF = (float*)d_out;
    __half2* w1  = (__half2*)d_ws;                               // 32 MiB
    __half2* s2  = w1 + (size_t)Bn * 131072;                     // 32 MiB
    __half2* w1c = s2 + (size_t)Bn * 131072;                     // 4 MiB

    k1b<<<Bn * 8 + Bn * 64, 256, 0, stream>>>(x, rpm, w1, w1c);
    k2<<<Bn * 64, 256, 0, stream>>>(w1, w1c, s2);
    k3<<<Bn * 32, 256, 0, stream>>>(s2, outF);
}

// Round 17
// 70.259 us; speedup vs baseline: 4.8295x; 1.0215x over previous
//
#include <hip/hip_runtime.h>
#include <hip/hip_fp16.h>
#include <math.h>

// EngineOrderFFT via batched Bluestein. |X| = |conv[:, :K]|. M=16384 as a
// 128x128 four-step, 3 kernel launches, line-complete global I/O (R8),
// fp16 intermediates (R9), LDS aliasing + in-block Bhat (R10), 16B/lane
// vector I/O (R12), k2 at 256thr/2-j-slice + fp16 w1c (R13).
// R16 = exact revert to R13 (best verified: 70.48us). R14 (fused grid
// barrier) and R15 (chirpT removal + k3 pipelining) both regressed.
//   W1[b][j][t1][ch] (half2), S2[b][t1][j][ch] (half2, 1/M pre-folded)
//   W1c[b][j][t1] (half2, chirp spectrum after pass 1)

static constexpr int Bn = 64;

#define PI_F 3.14159265358979323846f
#define TWO_PI_F 6.28318530717958647692f
#define R2_F 0.70710678118654752f

__device__ __forceinline__ int compute_n(float rpm) {
    // ref: pad = floor((40*60/rpm - 1)*8192) in f32; n = 8192 + pad
    return 8192 + (int)floorf((2400.0f / rpm - 1.0f) * 8192.0f);
}
__device__ __forceinline__ float2 cmul(float2 a, float2 b) {
    return make_float2(a.x*b.x - a.y*b.y, a.x*b.y + a.y*b.x);
}
__device__ __forceinline__ float2 cadd(float2 a, float2 b){ return make_float2(a.x+b.x, a.y+b.y); }
__device__ __forceinline__ float2 csub(float2 a, float2 b){ return make_float2(a.x-b.x, a.y-b.y); }
__device__ __forceinline__ float2 shflx1(float2 v) {
    return make_float2(__shfl_xor(v.x, 1, 64), __shfl_xor(v.y, 1, 64));
}
__device__ __forceinline__ int brev7(int x) { return (int)(__brev((unsigned)x) >> 25); }

// fp16 pack/unpack via 32-bit bit-cast (keeps global I/O in float4 lanes)
__device__ __forceinline__ float f2h_bits(float2 a) {
    union { __half2 h; float f; } u;
    u.h = __float22half2_rn(a);
    return u.f;
}
__device__ __forceinline__ float2 h2f_bits(float w) {
    union { float f; __half2 h; } u;
    u.f = w;
    return __half22float2(u.h);
}

#define BF(lo,hi,tw) { float2 _d = csub(lo,hi); lo = cadd(lo,hi); hi = cmul(_d, tw); }
#define BT(lo,hi,tw) { float2 _b = cmul(hi,tw); hi = csub(lo,_b); lo = cadd(lo,_b); }
#define SELC(r,c0,s0,c1,s1) ((r) ? make_float2(c1,s1) : make_float2(c0,s0))
#define IDX(u) ((u) + ((u) >> 4))          // row-local pad (R2/R3-proven)

// W_M^{-m}: Whi[m]=exp(-i*pi*m/64), Wlo[m]=exp(-i*pi*m/8192)
__device__ __forceinline__ float2 wtab(const float2* Whi, const float2* Wlo, int m) {
    return cmul(Whi[m >> 7], Wlo[m & 127]);
}

// ====== row-local cores. Lf = per-FFT scratch region (>=136 f2) ======
// HZ: inputs v[4..7] are implicit zeros (not loaded).
template<bool HZ>
__device__ __forceinline__ void difR(float2 v[8], float2* Lf, int p,
                                     const float2* sWhi) {
    float2 w1 = sWhi[p];                        // exp(-i*pi*p/64)
    float2 w2 = cmul(w1, w1);
    float2 w4 = cmul(w2, w2);
    float2 w1b = cmul(w1, make_float2(R2_F,-R2_F));
    float2 w1c = make_float2(w1.y, -w1.x);
    float2 w1d = cmul(w1, make_float2(-R2_F,-R2_F));
    float2 w2i = make_float2(w2.y, -w2.x);
    if (HZ) {
        v[4] = cmul(v[0], w1);
        v[5] = cmul(v[1], w1b);
        v[6] = cmul(v[2], w1c);
        v[7] = cmul(v[3], w1d);
    } else {
        BF(v[0],v[4], w1);
        BF(v[1],v[5], w1b);
        BF(v[2],v[6], w1c);
        BF(v[3],v[7], w1d);
    }
    BF(v[0],v[2], w2);  BF(v[1],v[3], w2i);
    BF(v[4],v[6], w2);  BF(v[5],v[7], w2i);
    BF(v[0],v[1], w4);  BF(v[2],v[3], w4);
    BF(v[4],v[5], w4);  BF(v[6],v[7], w4);
    #pragma unroll
    for (int q = 0; q < 8; ++q) Lf[IDX(p + 16*q)] = v[q];
    int bb = p >> 1, r = p & 1;
    #pragma unroll
    for (int s = 0; s < 8; ++s) v[s] = Lf[IDX(16*bb + r + 2*s)];
    BF(v[0],v[4], SELC(r, 1.f,0.f,                    0.92387953f,-0.38268343f));
    BF(v[1],v[5], SELC(r, 0.70710678f,-0.70710678f,   0.38268343f,-0.92387953f));
    BF(v[2],v[6], SELC(r, 0.f,-1.f,                  -0.38268343f,-0.92387953f));
    BF(v[3],v[7], SELC(r, -0.70710678f,-0.70710678f, -0.92387953f,-0.38268343f));
    BF(v[0],v[2], SELC(r, 1.f,0.f,  0.70710678f,-0.70710678f));
    BF(v[1],v[3], SELC(r, 0.f,-1.f, -0.70710678f,-0.70710678f));
    BF(v[4],v[6], SELC(r, 1.f,0.f,  0.70710678f,-0.70710678f));
    BF(v[5],v[7], SELC(r, 0.f,-1.f, -0.70710678f,-0.70710678f));
    #pragma unroll
    for (int s = 0; s < 8; s += 2) {
        float2 d = csub(v[s], v[s+1]);
        v[s] = cadd(v[s], v[s+1]);
        v[s+1] = r ? make_float2(d.y, -d.x) : d;
    }
    #pragma unroll
    for (int s = 0; s < 8; ++s) {
        float2 o = shflx1(v[s]);
        v[s] = r ? csub(o, v[s]) : cadd(v[s], o);
    }
}

// HOUT: only lo outputs v[0..3] of the final stage are produced.
template<bool HOUT>
__device__ __forceinline__ void ditR(float2 v[8], float2* Lf, int p,
                                     const float2* sWhi) {
    int bb = p >> 1, r = p & 1;
    #pragma unroll
    for (int s = 0; s < 8; ++s) {
        float2 o = shflx1(v[s]);
        v[s] = r ? csub(o, v[s]) : cadd(v[s], o);
    }
    #pragma unroll
    for (int s = 0; s < 8; s += 2) {
        float2 bq = v[s+1];
        if (r) bq = make_float2(-bq.y, bq.x);
        v[s+1] = csub(v[s], bq);
        v[s] = cadd(v[s], bq);
    }
    BT(v[0],v[2], SELC(r, 1.f,0.f,  0.70710678f,0.70710678f));
    BT(v[1],v[3], SELC(r, 0.f,1.f, -0.70710678f,0.70710678f));
    BT(v[4],v[6], SELC(r, 1.f,0.f,  0.70710678f,0.70710678f));
    BT(v[5],v[7], SELC(r, 0.f,1.f, -0.70710678f,0.70710678f));
    BT(v[0],v[4], SELC(r, 1.f,0.f,                   0.92387953f,0.38268343f));
    BT(v[1],v[5], SELC(r, 0.70710678f,0.70710678f,   0.38268343f,0.92387953f));
    BT(v[2],v[6], SELC(r, 0.f,1.f,                  -0.38268343f,0.92387953f));
    BT(v[3],v[7], SELC(r, -0.70710678f,0.70710678f, -0.92387953f,0.38268343f));
    #pragma unroll
    for (int s = 0; s < 8; ++s) Lf[IDX(16*bb + r + 2*s)] = v[s];
    #pragma unroll
    for (int q = 0; q < 8; ++q) v[q] = Lf[IDX(p + 16*q)];
    float2 w1 = make_float2(sWhi[p].x, -sWhi[p].y);   // exp(+i*pi*p/64)
    float2 w2 = cmul(w1, w1);
    float2 w4 = cmul(w2, w2);
    float2 w2j = make_float2(-w2.y, w2.x);
    float2 w1b = cmul(w1, make_float2(R2_F, R2_F));
    float2 w1c = make_float2(-w1.y, w1.x);
    float2 w1d = cmul(w1, make_float2(-R2_F, R2_F));
    BT(v[0],v[1], w4); BT(v[2],v[3], w4);
    BT(v[4],v[5], w4); BT(v[6],v[7], w4);
    BT(v[0],v[2], w2);  BT(v[1],v[3], w2j);
    BT(v[4],v[6], w2);  BT(v[5],v[7], w2j);
    if (HOUT) {
        v[0] = cadd(v[0], cmul(v[4], w1));
        v[1] = cadd(v[1], cmul(v[5], w1b));
        v[2] = cadd(v[2], cmul(v[6], w1c));
        v[3] = cadd(v[3], cmul(v[7], w1d));
    } else {
        BT(v[0],v[4], w1);
        BT(v[1],v[5], w1b);
        BT(v[2],v[6], w1c);
        BT(v[3],v[7], w1d);
    }
}

__device__ __forceinline__ void load_tabs(float2* sWhi, float2* sWlo, int tid) {
    if (tid < 128) {
        float sn, cs; __sincosf(PI_F * (float)tid * (1.0f/64.0f), &sn, &cs);
        sWhi[tid] = make_float2(cs, -sn);
    } else if (tid < 256) {
        int m = tid - 128;
        float sn, cs; __sincosf(PI_F * (float)m * (1.0f/8192.0f), &sn, &cs);
        sWlo[m] = make_float2(cs, -sn);
    }
}

// ---- K1B: merged launch. Blocks [0, Bn*8): bhat pass 1 (chirp -> FFT over
// t2 -> twiddle -> W1c fp16). Blocks [Bn*8, ...): main K1 (x -> chirp ->
// FFT over t2 -> twiddle -> W1 fp16). Both 256 thr, ~21 KB LDS.
__global__ __launch_bounds__(256) void k1b(const float* __restrict__ x,
                                           const float* __restrict__ rpm,
                                           __half2* __restrict__ w1,
                                           __half2* __restrict__ w1c) {
    __shared__ float2 Lw[16 * 137];            // aliased as Ls[128*17] later
    __shared__ float2 chirpT[128];
    __shared__ float2 sWhi[128];
    __shared__ float2 sWlo[128];
    int tid = threadIdx.x;
    int g = tid >> 4, p = tid & 15;
    int bb = p >> 1, r = p & 1;

    load_tabs(sWhi, sWlo, tid);

    if (blockIdx.x < Bn * 8) {
        // ======== bhat pass 1 ========
        int b = blockIdx.x >> 3;
        int t1_0 = (blockIdx.x & 7) << 4;
        int n = compute_n(rpm[b]);
        int two_n = 2 * n;
        float inv_n = 1.0f / (float)n;
        #pragma unroll
        for (int i = 0; i < 8; ++i) {
            int l = i * 256 + tid;
            int t2 = l >> 4, c = l & 15;
            int t = (t1_0 + c) + (t2 << 7);
            int mm = min(t, 16384 - t);
            int ph = (mm * mm) % two_n;
            float sn, cs; __sincosf(PI_F * (float)ph * inv_n, &sn, &cs);
            Lw[c * 137 + IDX(t2)] = make_float2(cs, sn);   // exp(+i b_phase)
        }
        __syncthreads();
        float2 v[8];
        #pragma unroll
        for (int q = 0; q < 8; ++q) v[q] = Lw[g * 137 + IDX(p + 16*q)];
        difR<false>(v, Lw + g * 137, p, sWhi);
        __syncthreads();                        // Lw dead -> alias as Ls
        {
            int t1 = t1_0 + g;
            int k2base = brev7(16*bb + r);
            float2 cur = wtab(sWhi, sWlo, t1 * k2base);
            float2 w8  = wtab(sWhi, sWlo, 8 * t1);
            #pragma unroll
            for (int e = 0; e < 8; ++e) {
                const int s = ((e & 1) << 2) | (e & 2) | ((e & 4) >> 2); // brev3
                Lw[(16*bb + r + 2*s) * 17 + g] = cmul(v[s], cur);
                cur = cmul(cur, w8);
            }
        }
        __syncthreads();
        {
            // w1c fp16: per j, 16 half2 = 4 float4 for this t1-group
            float4* wb4 = (float4*)(w1c + ((size_t)b << 14) + t1_0);
            #pragma unroll
            for (int i = 0; i < 2; ++i) {
                int l = i * 256 + tid;          // l < 512
                int j = l >> 2, w4 = l & 3;
                float4 val;
                val.x = f2h_bits(Lw[j * 17 + w4*4 + 0]);
                val.y = f2h_bits(Lw[j * 17 + w4*4 + 1]);
                val.z = f2h_bits(Lw[j * 17 + w4*4 + 2]);
                val.w = f2h_bits(Lw[j * 17 + w4*4 + 3]);
                wb4[(size_t)j * 32 + w4] = val;     // row stride 128 half2 = 32 f4
            }
        }
        return;
    }

    // ======== main K1 ========
    int bid = blockIdx.x - Bn * 8;
    int b = bid >> 6;
    int t1_0 = (bid & 63) << 1;
    int n = compute_n(rpm[b]);
    int two_n = 2 * n;
    float inv_n = 1.0f / (float)n;
    if (tid < 128) {
        int t2 = tid >> 1, t1l = tid & 1;
        int t = t1_0 + t1l + (t2 << 7);
        int ph = (t * t) % two_n;
        float sn, cs; __sincosf(PI_F * (float)ph * inv_n, &sn, &cs);
        chirpT[tid] = make_float2(cs, -sn);     // exp(-i a_phase)
    }
    __syncthreads();
    {
        // x loads: float4 = 4 ch, 16 B/lane; ONLY t2 < 64 (HZ trim)
        const float4* xb4 = (const float4*)(x + ((size_t)b << 16));
        int l = tid;                            // l < 256
        int t2 = l >> 2, rem = l & 3;
        int t1l = rem >> 1, cp = rem & 1;
        int t = t1_0 + t1l + (t2 << 7);         // t < 8192
        float4 xv = xb4[(size_t)t * 2 + cp];
        float2 u = chirpT[t2 * 2 + t1l];
        int c = t1l * 8 + cp * 4;
        Lw[c * 137 + IDX(t2)]       = make_float2(xv.x * u.x, xv.x * u.y);
        Lw[(c + 1) * 137 + IDX(t2)] = make_float2(xv.y * u.x, xv.y * u.y);
        Lw[(c + 2) * 137 + IDX(t2)] = make_float2(xv.z * u.x, xv.z * u.y);
        Lw[(c + 3) * 137 + IDX(t2)] = make_float2(xv.w * u.x, xv.w * u.y);
    }
    __syncthreads();
    float2 v[8];
    #pragma unroll
    for (int q = 0; q < 4; ++q) v[q] = Lw[g * 137 + IDX(p + 16*q)];
    difR<true>(v, Lw + g * 137, p, sWhi);
    __syncthreads();                            // Lw dead -> alias as Ls
    {
        int t1 = t1_0 + (g >> 3);
        int k2base = brev7(16*bb + r);
        float2 cur = wtab(sWhi, sWlo, t1 * k2base);
        float2 w8  = wtab(sWhi, sWlo, 8 * t1);
        #pragma unroll
        for (int e = 0; e < 8; ++e) {
            const int s = ((e & 1) << 2) | (e & 2) | ((e & 4) >> 2); // brev3(e)
            Lw[(16*bb + r + 2*s) * 17 + g] = cmul(v[s], cur);
            cur = cmul(cur, w8);
        }
    }
    __syncthreads();
    {
        // W1 writes: float4 = 4 half2, 16 B/lane; per j 64 B contiguous
        float4* wb4 = (float4*)(w1 + ((size_t)b << 17) + (t1_0 << 3));
        #pragma unroll
        for (int i = 0; i < 2; ++i) {
            int l = i * 256 + tid;              // l < 512
            int j = l >> 2, w4 = l & 3;
            float4 val;
            val.x = f2h_bits(Lw[j * 17 + w4*4 + 0]);
            val.y = f2h_bits(Lw[j * 17 + w4*4 + 1]);
            val.z = f2h_bits(Lw[j * 17 + w4*4 + 2]);
            val.w = f2h_bits(Lw[j * 17 + w4*4 + 3]);
            wb4[(size_t)j * 256 + w4] = val;
        }
    }
}

// ---- K2: block=(b, 2-j-slice), 256 thr, ~22 KB LDS (7 blocks/CU).
// W1 -> FFT over t1 -> *Bhat(in-block from W1c by groups g<2) -> iFFT ->
// twiddle*(1/M) -> S2 ----
__global__ __launch_bounds__(256) void k2(const __half2* __restrict__ w1,
                                          const __half2* __restrict__ w1c,
                                          __half2* __restrict__ s2) {
    __shared__ float2 Lw[16 * 137];            // aliased as Ls[128*17] later
    __shared__ float2 Wsc[2 * 137];            // Bhat scratch+result [s*17+p]
    __shared__ float2 sWhi[128];
    __shared__ float2 sWlo[128];
    int tid = threadIdx.x;
    int g = tid >> 4, p = tid & 15;             // g in [0,16): (jl = g>>3, ch = g&7)
    int b = blockIdx.x >> 6;
    int j0 = (blockIdx.x & 63) << 1;

    load_tabs(sWhi, sWlo, tid);
    // Bhat input prefetch (groups 0..1 <-> jl 0..1), fp16 w1c
    float2 vb[8];
    if (g < 2) {
        const __half2* wc = w1c + ((size_t)b << 14) + ((size_t)(j0 + g) << 7);
        #pragma unroll
        for (int q = 0; q < 8; ++q) vb[q] = __half22float2(wc[p + 16*q]);
    }
    // stage W1 (fp16): float4 = 4 half2, 16 B/lane, fully coalesced
    {
        const float4* rb4 = (const float4*)(w1 + ((size_t)b << 17) + ((size_t)j0 << 10));
        #pragma unroll
        for (int i = 0; i < 2; ++i) {
            int l = i * 256 + tid;              // l < 512
            int jl = l >> 8, rem = l & 255, t1 = rem >> 1, ch4 = rem & 1;
            float4 d = rb4[l];
            int c = jl * 8 + ch4 * 4;
            Lw[(c + 0) * 137 + IDX(t1)] = h2f_bits(d.x);
            Lw[(c + 1) * 137 + IDX(t1)] = h2f_bits(d.y);
            Lw[(c + 2) * 137 + IDX(t1)] = h2f_bits(d.z);
            Lw[(c + 3) * 137 + IDX(t1)] = h2f_bits(d.w);
        }
    }
    __syncthreads();
    // groups 0..1: 2 Bhat row-FFTs into Wsc (result layout [jl][s*17+p])
    if (g < 2) {
        difR<false>(vb, Wsc + g * 137, p, sWhi);
        #pragma unroll
        for (int s = 0; s < 8; ++s) Wsc[g * 137 + s * 17 + p] = vb[s];
    }
    // all: main forward FFT over t1
    float2* Lf = Lw + g * 137;
    float2 v[8];
    #pragma unroll
    for (int q = 0; q < 8; ++q) v[q] = Lf[IDX(p + 16*q)];
    difR<false>(v, Lf, p, sWhi);
    __syncthreads();                            // Wsc published
    {
        int jl = g >> 3;
        #pragma unroll
        for (int s = 0; s < 8; ++s) v[s] = cmul(v[s], Wsc[jl * 137 + s * 17 + p]);
    }
    ditR<false>(v, Lf, p, sWhi);
    int j = j0 + (g >> 3);
    int k2v = brev7(j);
    __syncthreads();                            // Lf scratch done -> alias Ls
    {
        float2 cur = wtab(sWhi, sWlo, k2v * p);
        float2 w16 = wtab(sWhi, sWlo, 16 * k2v);
        #pragma unroll
        for (int q = 0; q < 8; ++q) {
            // * exp(+2pi i k2 t1/M) * (1/M)  (scale folded for fp16 range)
            float2 tw = make_float2(cur.x * (1.0f/16384.0f), -cur.y * (1.0f/16384.0f));
            Lw[(p + 16*q) * 17 + g] = cmul(v[q], tw);
            cur = cmul(cur, w16);
        }
    }
    __syncthreads();
    {
        // S2 writes: float4 = 4 half2, 16 B/lane; per t1 64 B contiguous
        float4* sb4 = (float4*)(s2 + ((size_t)b << 17));
        #pragma unroll
        for (int i = 0; i < 2; ++i) {
            int l = i * 256 + tid;              // l < 512
            int t1 = l >> 2, w4 = l & 3;
            float4 val;
            val.x = f2h_bits(Lw[t1 * 17 + w4*4 + 0]);
            val.y = f2h_bits(Lw[t1 * 17 + w4*4 + 1]);
            val.z = f2h_bits(Lw[t1 * 17 + w4*4 + 2]);
            val.w = f2h_bits(Lw[t1 * 17 + w4*4 + 3]);
            sb4[(size_t)t1 * 256 + (j0 << 1) + w4] = val;
        }
    }
}

// ---- K3: block=(b, t1-pair). S2 -> iFFT over j -> |.| -> out ----
__global__ __launch_bounds__(256) void k3(const __half2* __restrict__ s2,
                                          float* __restrict__ outF) {
    __shared__ float2 Lw[16 * 137];            // aliased as float Lsf later
    __shared__ float2 sWhi[128];
    __shared__ float2 sWlo[128];
    int tid = threadIdx.x;
    int g = tid >> 4, p = tid & 15;
    int bb = p >> 1, r = p & 1;
    int b = blockIdx.x >> 6;
    int t1_0 = (blockIdx.x & 63) << 1;

    load_tabs(sWhi, sWlo, tid);
    {
        // S2 reads: float4 = 4 half2, 16 B/lane, fully coalesced
        const float4* rb4 = (const float4*)(s2 + ((size_t)b << 17) + ((size_t)t1_0 << 10));
        #pragma unroll
        for (int i = 0; i < 2; ++i) {
            int l = i * 256 + tid;              // l < 512
            int t1l = l >> 8, rem = l & 255, j = rem >> 1, ch4 = rem & 1;
            float4 d = rb4[l];
            int c = t1l * 8 + ch4 * 4;
            Lw[(c + 0) * 137 + IDX(j)] = h2f_bits(d.x);
            Lw[(c + 1) * 137 + IDX(j)] = h2f_bits(d.y);
            Lw[(c + 2) * 137 + IDX(j)] = h2f_bits(d.z);
            Lw[(c + 3) * 137 + IDX(j)] = h2f_bits(d.w);
        }
    }
    __syncthreads();
    float2 v[8];
    {
        float2* Lf = Lw + g * 137;
        #pragma unroll
        for (int s = 0; s < 8; ++s) v[s] = Lf[IDX(16*bb + r + 2*s)];
        ditR<true>(v, Lf, p, sWhi);
    }
    __syncthreads();                            // Lw dead -> alias float Lsf
    float* Lsf = (float*)Lw;
    #pragma unroll
    for (int q = 0; q < 4; ++q) {
        // v[q] = z[m = t1 + 128*(p+16q)], q<4 (1/M applied in k2)
        float2 z = v[q];
        Lsf[(p + 16*q) * 20 + g] = sqrtf(z.x*z.x + z.y*z.y);
    }
    __syncthreads();
    {
        // out writes: float4 = 4 ch, 16 B/lane; 64 B line-complete per (m)
        float4* ob4 = (float4*)(outF + ((size_t)b << 16) + (t1_0 << 3));
        int t2 = tid >> 2, t1l = (tid >> 1) & 1, ch4 = tid & 1;
        int base = t2 * 20 + t1l * 8 + ch4 * 4;
        float4 val = make_float4(Lsf[base], Lsf[base + 1], Lsf[base + 2], Lsf[base + 3]);
        ob4[t2 * 256 + t1l * 2 + ch4] = val;
    }
}

// ---------------- launch ----------------
extern "C" void kernel_launch(void* const* d_in, const int* in_sizes, int n_in,
                              void* d_out, int out_size, void* d_ws, size_t ws_size,
                              hipStream_t stream) {
    const float* x   = (const float*)d_in[0];
    const float* rpm = (const float*)d_in[1];
    float* outF = (float*)d_out;
    __half2* w1  = (__half2*)d_ws;                               // 32 MiB
    __half2* s2  = w1 + (size_t)Bn * 131072;                     // 32 MiB
    __half2* w1c = s2 + (size_t)Bn * 131072;                     // 4 MiB

    k1b<<<Bn * 8 + Bn * 64, 256, 0, stream>>>(x, rpm, w1, w1c);
    k2<<<Bn * 64, 256, 0, stream>>>(w1, w1c, s2);
    k3<<<Bn * 64, 256, 0, stream>>>(s2, outF);
}